// Round 1
// baseline (812.348 us; speedup 1.0000x reference)
//
#include <hip/hip_runtime.h>
#include <math.h>

namespace {
constexpr int BATCH = 4096;
constexpr int IN    = 1000;
constexpr int G     = 10;
constexpr int M     = 4;
constexpr int S     = 100;
constexpr int H     = 512;
constexpr int BB    = 8;        // batch rows per block
constexpr int HC    = 64;       // h per chunk
constexpr int NCH   = H / HC;   // 8
constexpr int HPAD  = 66;       // padded h-stride in LDS (bank-conflict-free-ish)
constexpr int NT    = 256;

struct __align__(16) Smem {
  float wx[BB][M][S];       // 12800 B : weighted x, s-major (float4-aligned rows)
  float wc[2][S][HPAD];     // 52800 B : W1/W2 chunk, TRANSPOSED [s][h]
};
} // namespace

__global__ __launch_bounds__(NT, 2)
void dfg_fused_kernel(const float* __restrict__ x,
                      const float* __restrict__ Wm,
                      const float* __restrict__ W1,
                      const float* __restrict__ W2,
                      const float* __restrict__ ln1w,
                      const float* __restrict__ ln1b,
                      const float* __restrict__ ln2w,
                      const float* __restrict__ ln2b,
                      float* __restrict__ out) {
  __shared__ Smem sm;
  const int tid = threadIdx.x;
  const int g   = blockIdx.y;
  const int b0  = blockIdx.x * BB;

  // Scratch views living inside wc (consumed before first W-chunk stage).
  float* xsm = &sm.wc[0][0][0];   // [BB][S]
  float* msm = xsm + BB * S;      // [M][S]

  // ---------- phase 0a: x slice -> LDS ; entmax(1.1) mask -> LDS ----------
  for (int i = tid; i < BB * S; i += NT) {
    int b = i / S, s = i - b * S;
    xsm[i] = x[(size_t)(b0 + b) * IN + g * S + s];
  }
  {
    const int wv = tid >> 6, l = tid & 63;     // wave wv owns mask row m=wv
    const float* wmp = Wm + (g * M + wv) * S;
    float v0 = (l < S)      ? wmp[l]      : -INFINITY;
    float v1 = (l + 64 < S) ? wmp[l + 64] : -INFINITY;
    float mx = fmaxf(v0, v1);
    #pragma unroll
    for (int d = 32; d >= 1; d >>= 1) mx = fmaxf(mx, __shfl_xor(mx, d));
    float e0 = (l < S)      ? expf(v0 - mx) : 0.f;
    float e1 = (l + 64 < S) ? expf(v1 - mx) : 0.f;
    float a0 = (l < S)      ? expf(1.1f * (v0 - mx)) : 0.f;
    float a1 = (l + 64 < S) ? expf(1.1f * (v1 - mx)) : 0.f;
    float ss = a0 + a1;
    #pragma unroll
    for (int d = 32; d >= 1; d >>= 1) ss += __shfl_xor(ss, d);
    float inv = 1.0f / powf(ss + 1e-5f, 1.0f / 1.1f);
    if (l < S)      msm[wv * S + l]      = e0 * inv;
    if (l + 64 < S) msm[wv * S + l + 64] = e1 * inv;
  }
  __syncthreads();
  // ---------- phase 0b: wx[b][m][s] = x[b][s] * mask[m][s] ----------
  for (int i = tid; i < BB * M * S; i += NT) {
    int b = i / (M * S); int rr = i - b * M * S; int m = rr / S; int s = rr - m * S;
    sm.wx[b][m][s] = xsm[b * S + s] * msm[m * S + s];
  }
  __syncthreads();

  // ---------- main: 8 h-chunks, W staged transposed in LDS ----------
  const int wv   = tid >> 6;
  const int l    = tid & 63;
  const int hl   = l & 31;       // 32 h-pair groups
  const int bml  = l >> 5;       // 2 b-subgroups per wave
  const int bloc = 2 * wv + bml; // 0..7 local batch row
  const int hb   = 2 * hl;       // h offset within chunk

  float acc1[NCH][2][M], acc2[NCH][2][M];
  #pragma unroll
  for (int c = 0; c < NCH; ++c)
    #pragma unroll
    for (int j = 0; j < 2; ++j)
      #pragma unroll
      for (int m = 0; m < M; ++m) { acc1[c][j][m] = 0.f; acc2[c][j][m] = 0.f; }

  const float* W1g = W1 + (size_t)g * H * S;
  const float* W2g = W2 + (size_t)g * H * S;

  #pragma unroll
  for (int c = 0; c < NCH; ++c) {
    // stage chunk c: contiguous [64][100] block of W1g/W2g -> transposed LDS
    const float4* g1 = (const float4*)(W1g + c * HC * S);
    const float4* g2 = (const float4*)(W2g + c * HC * S);
    for (int f = tid; f < HC * S / 4; f += NT) {
      float4 v1 = g1[f], v2 = g2[f];
      int e = f * 4;
      #pragma unroll
      for (int i = 0; i < 4; ++i) {
        int ee = e + i;
        int h = ee / S, s = ee - h * S;
        sm.wc[0][s][h] = (&v1.x)[i];
        sm.wc[1][s][h] = (&v2.x)[i];
      }
    }
    __syncthreads();

    const float* wxm = &sm.wx[bloc][0][0];   // this lane's [M][S]
    for (int s4 = 0; s4 < S / 4; ++s4) {
      float4 q0 = *(const float4*)(wxm + 0 * S + s4 * 4);
      float4 q1 = *(const float4*)(wxm + 1 * S + s4 * 4);
      float4 q2 = *(const float4*)(wxm + 2 * S + s4 * 4);
      float4 q3 = *(const float4*)(wxm + 3 * S + s4 * 4);
      #pragma unroll
      for (int j4 = 0; j4 < 4; ++j4) {
        int s = s4 * 4 + j4;
        float2 wa = *(const float2*)(&sm.wc[0][s][hb]);
        float2 wb = *(const float2*)(&sm.wc[1][s][hb]);
        float xs0 = (&q0.x)[j4], xs1 = (&q1.x)[j4];
        float xs2 = (&q2.x)[j4], xs3 = (&q3.x)[j4];
        acc1[c][0][0] += wa.x * xs0; acc1[c][1][0] += wa.y * xs0;
        acc1[c][0][1] += wa.x * xs1; acc1[c][1][1] += wa.y * xs1;
        acc1[c][0][2] += wa.x * xs2; acc1[c][1][2] += wa.y * xs2;
        acc1[c][0][3] += wa.x * xs3; acc1[c][1][3] += wa.y * xs3;
        acc2[c][0][0] += wb.x * xs0; acc2[c][1][0] += wb.y * xs0;
        acc2[c][0][1] += wb.x * xs1; acc2[c][1][1] += wb.y * xs1;
        acc2[c][0][2] += wb.x * xs2; acc2[c][1][2] += wb.y * xs2;
        acc2[c][0][3] += wb.x * xs3; acc2[c][1][3] += wb.y * xs3;
      }
    }
    __syncthreads();
  }

  // ---------- epilogue: LN stats (per b,m over 512 h) ----------
  float mu1[M], rs1[M], mu2[M], rs2[M];
  #pragma unroll
  for (int m = 0; m < M; ++m) {
    float s1 = 0.f, q1 = 0.f, s2 = 0.f, q2 = 0.f;
    #pragma unroll
    for (int c = 0; c < NCH; ++c)
      #pragma unroll
      for (int j = 0; j < 2; ++j) {
        float a = acc1[c][j][m], b = acc2[c][j][m];
        s1 += a; q1 += a * a; s2 += b; q2 += b * b;
      }
    #pragma unroll
    for (int d = 16; d >= 1; d >>= 1) {   // reduce within 32-lane half
      s1 += __shfl_xor(s1, d); q1 += __shfl_xor(q1, d);
      s2 += __shfl_xor(s2, d); q2 += __shfl_xor(q2, d);
    }
    mu1[m] = s1 * (1.0f / H);
    mu2[m] = s2 * (1.0f / H);
    float va = q1 * (1.0f / H) - mu1[m] * mu1[m];
    float vb = q2 * (1.0f / H) - mu2[m] * mu2[m];
    rs1[m] = rsqrtf(va + 1e-5f);
    rs2[m] = rsqrtf(vb + 1e-5f);
  }

  const float* lw1 = ln1w + g * H; const float* lb1 = ln1b + g * H;
  const float* lw2 = ln2w + g * H; const float* lb2 = ln2b + g * H;
  float* outp = out + (size_t)(b0 + bloc) * (G * H) + g * H;
  #pragma unroll
  for (int c = 0; c < NCH; ++c) {
    int h = c * HC + hb;
    float2 w1v = *(const float2*)(lw1 + h);
    float2 b1v = *(const float2*)(lb1 + h);
    float2 w2v = *(const float2*)(lw2 + h);
    float2 b2v = *(const float2*)(lb2 + h);
    float o0 = 0.f, o1 = 0.f;
    #pragma unroll
    for (int m = 0; m < M; ++m) {
      float n1a = (acc1[c][0][m] - mu1[m]) * rs1[m] * w1v.x + b1v.x;
      float n2a = (acc2[c][0][m] - mu2[m]) * rs2[m] * w2v.x + b2v.x;
      float sga = 1.0f / (1.0f + __expf(-n1a));
      o0 += fmaxf(sga * n2a, 0.f);
      float n1b = (acc1[c][1][m] - mu1[m]) * rs1[m] * w1v.y + b1v.y;
      float n2b = (acc2[c][1][m] - mu2[m]) * rs2[m] * w2v.y + b2v.y;
      float sgb = 1.0f / (1.0f + __expf(-n1b));
      o1 += fmaxf(sgb * n2b, 0.f);
    }
    *(float2*)(outp + h) = make_float2(o0, o1);
  }
}

extern "C" void kernel_launch(void* const* d_in, const int* in_sizes, int n_in,
                              void* d_out, int out_size, void* d_ws, size_t ws_size,
                              hipStream_t stream) {
  const float* x   = (const float*)d_in[0];
  const float* Wm  = (const float*)d_in[1];
  const float* W1  = (const float*)d_in[2];
  const float* W2  = (const float*)d_in[3];
  const float* l1w = (const float*)d_in[4];
  const float* l1b = (const float*)d_in[5];
  const float* l2w = (const float*)d_in[6];
  const float* l2b = (const float*)d_in[7];
  float* outp = (float*)d_out;
  dim3 grid(BATCH / BB, G);
  dfg_fused_kernel<<<grid, NT, 0, stream>>>(x, Wm, W1, W2, l1w, l1b, l2w, l2b, outp);
}

// Round 3
// 297.928 us; speedup vs baseline: 2.7267x; 2.7267x over previous
//
#include <hip/hip_runtime.h>
#include <math.h>

typedef _Float16 half8 __attribute__((ext_vector_type(8)));
typedef float f32x4 __attribute__((ext_vector_type(4)));

namespace {
constexpr int BATCH = 4096;
constexpr int IN  = 1000;
constexpr int G   = 10;
constexpr int M   = 4;
constexpr int S   = 100;
constexpr int H   = 512;
constexpr int BB  = 16;            // batch rows per block
constexpr int R   = 64;            // rows = BB*M  (r = m*16 + bl)
constexpr int NT  = 512;           // 8 waves
constexpr int APITCH = 136;        // wx LDS pitch in f16 (272 B -> 2-way banks)
constexpr int WPITCH = 40;         // W-chunk LDS pitch in f16 (80 B -> ~2-way)
constexpr int WX_BYTES = R * APITCH * 2;        // 17408
constexpr int WL_BYTES = 2 * H * WPITCH * 2;    // 81920
} // namespace

__global__ __launch_bounds__(NT, 2)
void dfg_mfma_kernel(const float* __restrict__ x,
                     const float* __restrict__ Wm,
                     const float* __restrict__ W1,
                     const float* __restrict__ W2,
                     const float* __restrict__ ln1w,
                     const float* __restrict__ ln1b,
                     const float* __restrict__ ln2w,
                     const float* __restrict__ ln2b,
                     float* __restrict__ out) {
  __shared__ __align__(16) char smem[WX_BYTES + WL_BYTES];   // 99328 B
  _Float16* wxs = (_Float16*)smem;               // [64][136] f16, K-padded wx
  _Float16* wl  = (_Float16*)(smem + WX_BYTES);  // [2][512][40] f16 W chunk
  float*    xs  = (float*)(smem + WX_BYTES);     // overlay: [16][100] x slice
  float*    msk = xs + BB * S;                   // overlay: [4][100] entmax mask
  float4*   red = (float4*)smem;                 // overlay: [64][9] LN partials
  float4*   fin = (float4*)(smem + 64 * 9 * 16); // overlay: [64] (mu1,rs1,mu2,rs2)

  const int tid = threadIdx.x;
  // XCD-chunked swizzle: consecutive blockIdx round-robin XCDs; give each XCD
  // a contiguous logical range so its L2 sees <=2 groups' W (2560 % 8 == 0).
  const int id      = blockIdx.x;
  const int logical = (id & 7) * 320 + (id >> 3);
  const int g  = logical >> 8;          // /256 batch-blocks per group
  const int b0 = (logical & 255) * BB;

  const int wv = tid >> 6, l = tid & 63;
  const int lo = l & 15, hi = l >> 4;

  // ---------------- phase 0: x slice -> LDS, entmax mask -> LDS -------------
  for (int f = tid; f < BB * 25; f += NT) {      // 400 float4
    int bl = f / 25, s4 = f - bl * 25;
    *(float4*)&xs[bl * S + s4 * 4] =
        *(const float4*)(x + (size_t)(b0 + bl) * IN + g * S + s4 * 4);
  }
  if (wv < 4) {                                  // wave wv owns mask row m=wv
    const float* wmp = Wm + (g * M + wv) * S;
    float v0 = (l < S) ? wmp[l] : -INFINITY;
    float v1 = (l + 64 < S) ? wmp[l + 64] : -INFINITY;
    float mx = fmaxf(v0, v1);
    #pragma unroll
    for (int d = 32; d >= 1; d >>= 1) mx = fmaxf(mx, __shfl_xor(mx, d));
    float e0 = (l < S) ? expf(v0 - mx) : 0.f;
    float e1 = (l + 64 < S) ? expf(v1 - mx) : 0.f;
    float a0 = (l < S) ? expf(1.1f * (v0 - mx)) : 0.f;
    float a1 = (l + 64 < S) ? expf(1.1f * (v1 - mx)) : 0.f;
    float ss = a0 + a1;
    #pragma unroll
    for (int d = 32; d >= 1; d >>= 1) ss += __shfl_xor(ss, d);
    float inv = 1.0f / powf(ss + 1e-5f, 1.0f / 1.1f);
    if (l < S) msk[wv * S + l] = e0 * inv;
    if (l + 64 < S) msk[wv * S + l + 64] = e1 * inv;
  }
  __syncthreads();

  // ---------------- phase 1: wx[r][k] = x[bl][s]*mask[m][s] -> f16 ----------
  {
    const int r = tid & 63;                  // row r = m*16 + bl
    const int c = tid >> 6;                  // s-chunk 0..7 (13 elems, last 9)
    const int bl = r & 15, m = r >> 4;
    const int sBeg = c * 13;
    const int sEnd = (sBeg + 13 < S) ? sBeg + 13 : S;
    for (int s = sBeg; s < sEnd; ++s)
      wxs[r * APITCH + s] = (_Float16)(xs[bl * S + s] * msk[m * S + s]);
  }
  for (int f = tid; f < R * 14; f += NT) {   // zero K-pad 100..127 (as uints)
    int r = f / 14, j = f - r * 14;
    *(unsigned int*)&wxs[r * APITCH + 100 + j * 2] = 0u;
  }
  __syncthreads();

  // ---------------- main: 4 K-steps of 32, W f32->f16 staged per step -------
  f32x4 acc1[4][4] = {};                     // [h-tile][r-tile] (r-tile == m)
  f32x4 acc2[4][4] = {};
  const float* W1g = W1 + (size_t)g * H * S;
  const float* W2g = W2 + (size_t)g * H * S;

  #pragma unroll
  for (int ks = 0; ks < 4; ++ks) {
    #pragma unroll
    for (int mat = 0; mat < 2; ++mat) {
      const float* Wg = mat ? W2g : W1g;
      #pragma unroll
      for (int i = 0; i < 8; ++i) {
        int f = tid + i * NT;                // 0..4095: h = f>>3, s4 = f&7
        int h = f >> 3, s4 = f & 7;
        union { _Float16 hh[4]; unsigned int u[2]; } pk;
        if (ks < 3 || s4 == 0) {             // last step: only s=96..99 valid
          float4 v = *(const float4*)(Wg + h * S + ks * 32 + s4 * 4);
          pk.hh[0] = (_Float16)v.x; pk.hh[1] = (_Float16)v.y;
          pk.hh[2] = (_Float16)v.z; pk.hh[3] = (_Float16)v.w;
        } else { pk.u[0] = 0u; pk.u[1] = 0u; }
        *(uint2*)&wl[mat * H * WPITCH + h * WPITCH + s4 * 4] = *(uint2*)pk.u;
      }
    }
    __syncthreads();

    // wave wv owns h in [64*wv, 64*wv+64); all 64 rows; both mats.
    half8 xf[4];
    #pragma unroll
    for (int rt = 0; rt < 4; ++rt)           // B-operand: col r = rt*16+lo
      xf[rt] = *(const half8*)&wxs[(rt * 16 + lo) * APITCH + ks * 32 + 8 * hi];
    #pragma unroll
    for (int ht = 0; ht < 4; ++ht) {
      const int hrow = 64 * wv + ht * 16 + lo;   // A-operand: row h
      half8 wf1 = *(const half8*)&wl[hrow * WPITCH + 8 * hi];
      half8 wf2 = *(const half8*)&wl[H * WPITCH + hrow * WPITCH + 8 * hi];
      #pragma unroll
      for (int rt = 0; rt < 4; ++rt) {
        acc1[ht][rt] = __builtin_amdgcn_mfma_f32_16x16x32_f16(wf1, xf[rt], acc1[ht][rt], 0, 0, 0);
        acc2[ht][rt] = __builtin_amdgcn_mfma_f32_16x16x32_f16(wf2, xf[rt], acc2[ht][rt], 0, 0, 0);
      }
    }
    __syncthreads();
  }

  // ------------- epilogue: LN stats (D-tile: col r=rt*16+lo, h=4*hi+rg) -----
  float st1[4], sq1[4], st2[4], sq2[4];
  #pragma unroll
  for (int rt = 0; rt < 4; ++rt) {
    float s1 = 0.f, q1 = 0.f, s2 = 0.f, q2 = 0.f;
    #pragma unroll
    for (int ht = 0; ht < 4; ++ht)
      #pragma unroll
      for (int rg = 0; rg < 4; ++rg) {
        float a = acc1[ht][rt][rg], b = acc2[ht][rt][rg];
        s1 += a; q1 += a * a; s2 += b; q2 += b * b;
      }
    st1[rt] = s1; sq1[rt] = q1; st2[rt] = s2; sq2[rt] = q2;
  }
  #pragma unroll
  for (int d = 16; d <= 32; d <<= 1) {       // reduce across hi groups (4 lanes)
    #pragma unroll
    for (int rt = 0; rt < 4; ++rt) {
      st1[rt] += __shfl_xor(st1[rt], d); sq1[rt] += __shfl_xor(sq1[rt], d);
      st2[rt] += __shfl_xor(st2[rt], d); sq2[rt] += __shfl_xor(sq2[rt], d);
    }
  }
  if (hi == 0) {                              // one writer per (row, wave)
    #pragma unroll
    for (int rt = 0; rt < 4; ++rt)
      red[(rt * 16 + lo) * 9 + wv] = make_float4(st1[rt], sq1[rt], st2[rt], sq2[rt]);
  }
  __syncthreads();
  if (tid < 64) {                             // combine 8 waves, finalize row
    float4 t = make_float4(0.f, 0.f, 0.f, 0.f);
    #pragma unroll
    for (int j = 0; j < 8; ++j) {
      float4 v = red[tid * 9 + j];
      t.x += v.x; t.y += v.y; t.z += v.z; t.w += v.w;
    }
    float mu1 = t.x * (1.f / H), mu2 = t.z * (1.f / H);
    float va = t.y * (1.f / H) - mu1 * mu1;
    float vb = t.w * (1.f / H) - mu2 * mu2;
    fin[tid] = make_float4(mu1, rsqrtf(va + 1e-5f), mu2, rsqrtf(vb + 1e-5f));
  }
  __syncthreads();

  // ------------- normalize, sigmoid*relu, sum over m (=rt), store -----------
  float4 fr[4];
  #pragma unroll
  for (int rt = 0; rt < 4; ++rt) fr[rt] = fin[rt * 16 + lo];
  const float* p1w = ln1w + g * H; const float* p1b = ln1b + g * H;
  const float* p2w = ln2w + g * H; const float* p2b = ln2b + g * H;
  float* orow = out + (size_t)(b0 + lo) * (G * H) + g * H;
  #pragma unroll
  for (int ht = 0; ht < 4; ++ht) {
    const int hb = 64 * wv + ht * 16 + 4 * hi;
    float4 w1v = *(const float4*)(p1w + hb);
    float4 b1v = *(const float4*)(p1b + hb);
    float4 w2v = *(const float4*)(p2w + hb);
    float4 b2v = *(const float4*)(p2b + hb);
    float o[4] = {0.f, 0.f, 0.f, 0.f};
    #pragma unroll
    for (int rt = 0; rt < 4; ++rt) {
      #pragma unroll
      for (int rg = 0; rg < 4; ++rg) {
        float n1 = (acc1[ht][rt][rg] - fr[rt].x) * fr[rt].y * (&w1v.x)[rg] + (&b1v.x)[rg];
        float n2 = (acc2[ht][rt][rg] - fr[rt].z) * fr[rt].w * (&w2v.x)[rg] + (&b2v.x)[rg];
        float sg = 1.0f / (1.0f + __expf(-n1));
        o[rg] += fmaxf(sg * n2, 0.f);
      }
    }
    *(float4*)(orow + hb) = make_float4(o[0], o[1], o[2], o[3]);
  }
}

extern "C" void kernel_launch(void* const* d_in, const int* in_sizes, int n_in,
                              void* d_out, int out_size, void* d_ws, size_t ws_size,
                              hipStream_t stream) {
  const float* x   = (const float*)d_in[0];
  const float* Wm  = (const float*)d_in[1];
  const float* W1  = (const float*)d_in[2];
  const float* W2  = (const float*)d_in[3];
  const float* l1w = (const float*)d_in[4];
  const float* l1b = (const float*)d_in[5];
  const float* l2w = (const float*)d_in[6];
  const float* l2b = (const float*)d_in[7];
  float* outp = (float*)d_out;
  dfg_mfma_kernel<<<(BATCH / BB) * G, NT, 0, stream>>>(
      x, Wm, W1, W2, l1w, l1b, l2w, l2b, outp);
}

// Round 6
// 285.462 us; speedup vs baseline: 2.8457x; 1.0437x over previous
//
#include <hip/hip_runtime.h>
#include <math.h>

typedef _Float16 half8 __attribute__((ext_vector_type(8)));
typedef float f32x4 __attribute__((ext_vector_type(4)));

namespace {
constexpr int BATCH = 4096;
constexpr int IN  = 1000;
constexpr int G   = 10;
constexpr int M   = 4;
constexpr int S   = 100;
constexpr int H   = 512;
constexpr int BB  = 16;            // batch rows per block
constexpr int R   = 64;            // rows = BB*M ; r = m*16 + bl
constexpr int NT  = 512;           // 8 waves; wave wv owns h in [64*wv, 64*wv+64)
constexpr int KP  = 128;           // padded K in pre-converted W (f16)
constexpr int WXP = 136;           // wx LDS pitch in f16 (272 B -> 2-way banks)
constexpr int OFF_XS  = R * WXP * 2;            // 17408: wxs region size
constexpr int OFF_MSK = OFF_XS + BB * S * 4;    // +6400
constexpr int LDS_SZ  = OFF_MSK + M * S * 4;    // +1600 = 25408 B
constexpr int OFF_FIN = 64 * 9 * 16;            // 9216 (red pitch 9 float4)
constexpr size_t WMAT = (size_t)G * H * KP;     // f16 elems per mat
constexpr size_t W16_BYTES = 2 * WMAT * sizeof(_Float16);  // 2,621,440
} // namespace

// ---------------- pre-pass: W1,W2 f32 -> f16 [mat][g][h][128], zero-padded ---
__global__ __launch_bounds__(256)
void cvt_w_kernel(const float* __restrict__ W1, const float* __restrict__ W2,
                  _Float16* __restrict__ w16) {
  const int t = blockIdx.x * 256 + threadIdx.x;     // one half8 chunk each
  const int c = t & 15;                             // k-chunk (8 f16)
  const int row = t >> 4;                           // mat*5120 + g*512 + h
  const int mat = row / (G * H);
  const int r2  = row - mat * (G * H);
  const float* src = (mat ? W2 : W1) + (size_t)r2 * S;
  union { _Float16 h[8]; uint4 u; } o;
  #pragma unroll
  for (int j = 0; j < 8; ++j) {
    const int k = c * 8 + j;
    o.h[j] = (k < S) ? (_Float16)src[k] : (_Float16)0.f;
  }
  *(uint4*)&w16[(size_t)row * KP + c * 8] = o.u;
}

__device__ inline half8 pk8(float4 a, float4 b) {
  half8 r;
  r[0] = (_Float16)a.x; r[1] = (_Float16)a.y; r[2] = (_Float16)a.z; r[3] = (_Float16)a.w;
  r[4] = (_Float16)b.x; r[5] = (_Float16)b.y; r[6] = (_Float16)b.z; r[7] = (_Float16)b.w;
  return r;
}

// ---------------- main fused kernel -----------------------------------------
// PRE=1: A-frags from pre-converted f16 workspace. PRE=0: f32 W + inline cvt.
template <bool PRE>
__global__ __launch_bounds__(NT, 2)
void dfg_mfma3_kernel(const float* __restrict__ x,
                      const float* __restrict__ Wm,
                      const _Float16* __restrict__ w16,
                      const float* __restrict__ W1f,
                      const float* __restrict__ W2f,
                      const float* __restrict__ ln1w,
                      const float* __restrict__ ln1b,
                      const float* __restrict__ ln2w,
                      const float* __restrict__ ln2b,
                      float* __restrict__ out) {
  __shared__ __align__(16) char smem[LDS_SZ];
  _Float16* wxs = (_Float16*)smem;                 // [64][136] f16
  float*    xs  = (float*)(smem + OFF_XS);         // [16][100] f32
  float*    msk = (float*)(smem + OFF_MSK);        // [4][100] f32
  float4*   red = (float4*)smem;                   // overlay: [64][9] partials
  float4*   fin = (float4*)(smem + OFF_FIN);       // overlay: [64] row params

  const int tid = threadIdx.x;
  // XCD-chunked swizzle (2560 % 8 == 0 -> bijective)
  const int id      = blockIdx.x;
  const int logical = (id & 7) * 320 + (id >> 3);
  const int g  = logical >> 8;                     // 256 blocks per group
  const int b0 = (logical & 255) * BB;

  const int wv = tid >> 6, l = tid & 63;
  const int lo = l & 15, hi = l >> 4;

  // ---- phase 0: x slice -> LDS ; entmax(1.1) mask -> LDS --------------------
  for (int f = tid; f < BB * 25; f += NT) {        // 400 float4
    int bl = f / 25, s4 = f - bl * 25;
    *(float4*)&xs[bl * S + s4 * 4] =
        *(const float4*)(x + (size_t)(b0 + bl) * IN + g * S + s4 * 4);
  }
  if (wv < 4) {                                    // wave wv owns mask row m=wv
    const float* wmp = Wm + (g * M + wv) * S;
    float v0 = (l < S) ? wmp[l] : -INFINITY;
    float v1 = (l + 64 < S) ? wmp[l + 64] : -INFINITY;
    float mx = fmaxf(v0, v1);
    #pragma unroll
    for (int d = 32; d >= 1; d >>= 1) mx = fmaxf(mx, __shfl_xor(mx, d));
    float e0 = (l < S) ? expf(v0 - mx) : 0.f;
    float e1 = (l + 64 < S) ? expf(v1 - mx) : 0.f;
    float a0 = (l < S) ? expf(1.1f * (v0 - mx)) : 0.f;
    float a1 = (l + 64 < S) ? expf(1.1f * (v1 - mx)) : 0.f;
    float ss = a0 + a1;
    #pragma unroll
    for (int d = 32; d >= 1; d >>= 1) ss += __shfl_xor(ss, d);
    float inv = 1.0f / powf(ss + 1e-5f, 1.0f / 1.1f);
    if (l < S) msk[wv * S + l] = e0 * inv;
    if (l + 64 < S) msk[wv * S + l + 64] = e1 * inv;
  }
  __syncthreads();

  // ---- phase 1: wx[r][k] = x[bl][k] * msk[m][k] -> f16 (K-pad to 128) -------
  {
    const int r = tid >> 3;                        // 0..63 ; r = m*16 + bl
    const int j = tid & 7;                         // k-chunk of 16
    const int bl = r & 15, m = r >> 4;
    union { _Float16 h[16]; uint4 u[2]; } o;
    #pragma unroll
    for (int i = 0; i < 16; ++i) {
      const int k = j * 16 + i;
      float v = 0.f;
      if (k < S) v = xs[bl * S + k] * msk[m * S + k];
      o.h[i] = (_Float16)v;
    }
    *(uint4*)&wxs[r * WXP + j * 16]     = o.u[0];
    *(uint4*)&wxs[r * WXP + j * 16 + 8] = o.u[1];
  }
  __syncthreads();

  // ---- main: 4 K-steps; W A-frags straight from L2; NO barriers ------------
  f32x4 acc1[4][4] = {};                           // [ht][rt] (rt == m)
  f32x4 acc2[4][4] = {};
  const _Float16* w1p = PRE ? w16 + (size_t)g * H * KP : nullptr;
  const _Float16* w2p = PRE ? w1p + WMAT : nullptr;
  const float* W1g = W1f + (size_t)g * H * S;
  const float* W2g = W2f + (size_t)g * H * S;

  #pragma unroll
  for (int ks = 0; ks < 4; ++ks) {
    half8 xf[4];
    #pragma unroll
    for (int rt = 0; rt < 4; ++rt)                 // B-frag: col r = rt*16+lo
      xf[rt] = *(const half8*)&wxs[(rt * 16 + lo) * WXP + ks * 32 + 8 * hi];
    #pragma unroll
    for (int ht = 0; ht < 4; ++ht) {
      const int hrow = 64 * wv + ht * 16 + lo;     // A-frag: row h
      half8 wf1, wf2;
      if constexpr (PRE) {
        wf1 = *(const half8*)&w1p[(size_t)hrow * KP + ks * 32 + 8 * hi];
        wf2 = *(const half8*)&w2p[(size_t)hrow * KP + ks * 32 + 8 * hi];
      } else {
        const float* s1 = W1g + (size_t)hrow * S + ks * 32 + 8 * hi;
        const float* s2 = W2g + (size_t)hrow * S + ks * 32 + 8 * hi;
        if (ks < 3) {                              // k <= 95: fully in-bounds
          wf1 = pk8(*(const float4*)s1, *(const float4*)(s1 + 4));
          wf2 = pk8(*(const float4*)s2, *(const float4*)(s2 + 4));
        } else if (hi == 0) {                      // k = 96..103: half valid
          float4 z = make_float4(0.f, 0.f, 0.f, 0.f);
          wf1 = pk8(*(const float4*)s1, z);
          wf2 = pk8(*(const float4*)s2, z);
        } else {                                   // k >= 104: all pad
          half8 zz = {};
          wf1 = zz; wf2 = zz;
        }
      }
      #pragma unroll
      for (int rt = 0; rt < 4; ++rt) {
        acc1[ht][rt] = __builtin_amdgcn_mfma_f32_16x16x32_f16(wf1, xf[rt], acc1[ht][rt], 0, 0, 0);
        acc2[ht][rt] = __builtin_amdgcn_mfma_f32_16x16x32_f16(wf2, xf[rt], acc2[ht][rt], 0, 0, 0);
      }
    }
  }
  __syncthreads();                                 // wxs reads done -> overlay ok

  // ---- LN stats: per row r, reduce over h = {wv} x {ht} x {hi} x {rg} -------
  float st1[4], sq1[4], st2[4], sq2[4];
  #pragma unroll
  for (int rt = 0; rt < 4; ++rt) {
    float s1 = 0.f, q1 = 0.f, s2 = 0.f, q2 = 0.f;
    #pragma unroll
    for (int ht = 0; ht < 4; ++ht)
      #pragma unroll
      for (int rg = 0; rg < 4; ++rg) {
        float a = acc1[ht][rt][rg], b = acc2[ht][rt][rg];
        s1 += a; q1 += a * a; s2 += b; q2 += b * b;
      }
    st1[rt] = s1; sq1[rt] = q1; st2[rt] = s2; sq2[rt] = q2;
  }
  #pragma unroll
  for (int d = 16; d <= 32; d <<= 1) {             // sum over hi lane-groups
    #pragma unroll
    for (int rt = 0; rt < 4; ++rt) {
      st1[rt] += __shfl_xor(st1[rt], d); sq1[rt] += __shfl_xor(sq1[rt], d);
      st2[rt] += __shfl_xor(st2[rt], d); sq2[rt] += __shfl_xor(sq2[rt], d);
    }
  }
  if (hi == 0) {                                   // one writer per (row, wave)
    #pragma unroll
    for (int rt = 0; rt < 4; ++rt)
      red[(rt * 16 + lo) * 9 + wv] = make_float4(st1[rt], sq1[rt], st2[rt], sq2[rt]);
  }
  __syncthreads();
  if (tid < 64) {                                  // combine 8 waves per row
    float4 t = make_float4(0.f, 0.f, 0.f, 0.f);
    #pragma unroll
    for (int j = 0; j < 8; ++j) {
      float4 v = red[tid * 9 + j];
      t.x += v.x; t.y += v.y; t.z += v.z; t.w += v.w;
    }
    float mu1 = t.x * (1.f / H), mu2 = t.z * (1.f / H);
    float va = t.y * (1.f / H) - mu1 * mu1;
    float vb = t.w * (1.f / H) - mu2 * mu2;
    fin[tid] = make_float4(mu1, rsqrtf(va + 1e-5f), mu2, rsqrtf(vb + 1e-5f));
  }
  __syncthreads();

  // ---- normalize, sigmoid*relu, sum over m (=rt), store ---------------------
  float4 fr[4];
  #pragma unroll
  for (int rt = 0; rt < 4; ++rt) fr[rt] = fin[rt * 16 + lo];
  const float* p1w = ln1w + g * H; const float* p1b = ln1b + g * H;
  const float* p2w = ln2w + g * H; const float* p2b = ln2b + g * H;
  float* orow = out + (size_t)(b0 + lo) * (G * H) + g * H;
  #pragma unroll
  for (int ht = 0; ht < 4; ++ht) {
    const int hb = 64 * wv + ht * 16 + 4 * hi;
    float4 w1v = *(const float4*)(p1w + hb);
    float4 b1v = *(const float4*)(p1b + hb);
    float4 w2v = *(const float4*)(p2w + hb);
    float4 b2v = *(const float4*)(p2b + hb);
    float o[4] = {0.f, 0.f, 0.f, 0.f};
    #pragma unroll
    for (int rt = 0; rt < 4; ++rt) {
      #pragma unroll
      for (int rg = 0; rg < 4; ++rg) {
        float n1 = (acc1[ht][rt][rg] - fr[rt].x) * fr[rt].y * (&w1v.x)[rg] + (&b1v.x)[rg];
        float n2 = (acc2[ht][rt][rg] - fr[rt].z) * fr[rt].w * (&w2v.x)[rg] + (&b2v.x)[rg];
        float sg = 1.0f / (1.0f + __expf(-n1));
        o[rg] += fmaxf(sg * n2, 0.f);
      }
    }
    *(float4*)(orow + hb) = make_float4(o[0], o[1], o[2], o[3]);
  }
}

extern "C" void kernel_launch(void* const* d_in, const int* in_sizes, int n_in,
                              void* d_out, int out_size, void* d_ws, size_t ws_size,
                              hipStream_t stream) {
  const float* x   = (const float*)d_in[0];
  const float* Wm  = (const float*)d_in[1];
  const float* W1  = (const float*)d_in[2];
  const float* W2  = (const float*)d_in[3];
  const float* l1w = (const float*)d_in[4];
  const float* l1b = (const float*)d_in[5];
  const float* l2w = (const float*)d_in[6];
  const float* l2b = (const float*)d_in[7];
  float* outp = (float*)d_out;

  const dim3 grid((BATCH / BB) * G);
  if (ws_size >= W16_BYTES && d_ws != nullptr) {
    _Float16* w16 = (_Float16*)d_ws;
    const int cvt_threads = 2 * G * H * (KP / 8);  // 163840
    cvt_w_kernel<<<cvt_threads / 256, 256, 0, stream>>>(W1, W2, w16);
    dfg_mfma3_kernel<true><<<grid, NT, 0, stream>>>(
        x, Wm, w16, W1, W2, l1w, l1b, l2w, l2b, outp);
  } else {
    dfg_mfma3_kernel<false><<<grid, NT, 0, stream>>>(
        x, Wm, nullptr, W1, W2, l1w, l1b, l2w, l2b, outp);
  }
}

// Round 9
// 265.837 us; speedup vs baseline: 3.0558x; 1.0738x over previous
//
#include <hip/hip_runtime.h>
#include <math.h>

typedef _Float16 half8 __attribute__((ext_vector_type(8)));
typedef float f32x4 __attribute__((ext_vector_type(4)));

namespace {
constexpr int BATCH = 4096;
constexpr int IN  = 1000;
constexpr int G   = 10;
constexpr int M   = 4;
constexpr int S   = 100;
constexpr int H   = 512;
constexpr int BB  = 16;            // batch rows per block
constexpr int R   = 64;            // rows = BB*M ; r = m*16 + bl
constexpr int NT  = 512;           // 8 waves; wave wv owns h in [64*wv, 64*wv+64)
constexpr int KP  = 128;           // padded K in pre-converted W (f16)
constexpr int WXP = 136;           // wx LDS pitch in f16 (272 B -> 2-way banks)
constexpr int OFF_XS  = R * WXP * 2;            // 17408: wxs region size
constexpr int OFF_MSK = OFF_XS + BB * S * 4;    // +6400
constexpr int LDS_SZ  = OFF_MSK + M * S * 4;    // +1600 = 25408 B
constexpr int OFF_FIN = 64 * 9 * 16;            // 9216 (red pitch 9 float4)
constexpr size_t WMAT = (size_t)G * H * KP;     // f16 elems per mat
constexpr size_t W16_BYTES = 2 * WMAT * sizeof(_Float16);  // 2,621,440
} // namespace

// ---------------- pre-pass: W1,W2 f32 -> f16 [mat][g][h][128], zero-padded ---
__global__ __launch_bounds__(256)
void cvt_w_kernel(const float* __restrict__ W1, const float* __restrict__ W2,
                  _Float16* __restrict__ w16) {
  const int t = blockIdx.x * 256 + threadIdx.x;     // one half8 chunk each
  const int c = t & 15;                             // k-chunk (8 f16)
  const int row = t >> 4;                           // mat*5120 + g*512 + h
  const int mat = row / (G * H);
  const int r2  = row - mat * (G * H);
  const float* src = (mat ? W2 : W1) + (size_t)r2 * S;
  union { _Float16 h[8]; uint4 u; } o;
  #pragma unroll
  for (int j = 0; j < 8; ++j) {
    const int k = c * 8 + j;
    o.h[j] = (k < S) ? (_Float16)src[k] : (_Float16)0.f;
  }
  *(uint4*)&w16[(size_t)row * KP + c * 8] = o.u;
}

__device__ inline half8 pk8(float4 a, float4 b) {
  half8 r;
  r[0] = (_Float16)a.x; r[1] = (_Float16)a.y; r[2] = (_Float16)a.z; r[3] = (_Float16)a.w;
  r[4] = (_Float16)b.x; r[5] = (_Float16)b.y; r[6] = (_Float16)b.z; r[7] = (_Float16)b.w;
  return r;
}

// ---------------- main fused kernel -----------------------------------------
// PRE=1: A-frags from pre-converted f16 workspace. PRE=0: f32 W + inline cvt.
template <bool PRE>
__global__ __launch_bounds__(NT, 1)
void dfg_mfma4_kernel(const float* __restrict__ x,
                      const float* __restrict__ Wm,
                      const _Float16* __restrict__ w16,
                      const float* __restrict__ W1f,
                      const float* __restrict__ W2f,
                      const float* __restrict__ ln1w,
                      const float* __restrict__ ln1b,
                      const float* __restrict__ ln2w,
                      const float* __restrict__ ln2b,
                      float* __restrict__ out) {
  __shared__ __align__(16) char smem[LDS_SZ];
  _Float16* wxs = (_Float16*)smem;                 // [64][136] f16
  float*    xs  = (float*)(smem + OFF_XS);         // [16][100] f32
  float*    msk = (float*)(smem + OFF_MSK);        // [4][100] f32
  float4*   red = (float4*)smem;                   // overlay: [64][9] partials
  float4*   fin = (float4*)(smem + OFF_FIN);       // overlay: [64] row params

  const int tid = threadIdx.x;
  // XCD-chunked swizzle (2560 % 8 == 0 -> bijective)
  const int id      = blockIdx.x;
  const int logical = (id & 7) * 320 + (id >> 3);
  const int g  = logical >> 8;                     // 256 blocks per group
  const int b0 = (logical & 255) * BB;

  const int wv = tid >> 6, l = tid & 63;
  const int lo = l & 15, hi = l >> 4;

  // ---- phase 0: x slice -> LDS ; entmax(1.1) mask -> LDS --------------------
  for (int f = tid; f < BB * 25; f += NT) {        // 400 float4
    int bl = f / 25, s4 = f - bl * 25;
    *(float4*)&xs[bl * S + s4 * 4] =
        *(const float4*)(x + (size_t)(b0 + bl) * IN + g * S + s4 * 4);
  }
  if (wv < 4) {                                    // wave wv owns mask row m=wv
    const float* wmp = Wm + (g * M + wv) * S;
    float v0 = (l < S) ? wmp[l] : -INFINITY;
    float v1 = (l + 64 < S) ? wmp[l + 64] : -INFINITY;
    float mx = fmaxf(v0, v1);
    #pragma unroll
    for (int d = 32; d >= 1; d >>= 1) mx = fmaxf(mx, __shfl_xor(mx, d));
    float e0 = (l < S) ? expf(v0 - mx) : 0.f;
    float e1 = (l + 64 < S) ? expf(v1 - mx) : 0.f;
    float a0 = (l < S) ? expf(1.1f * (v0 - mx)) : 0.f;
    float a1 = (l + 64 < S) ? expf(1.1f * (v1 - mx)) : 0.f;
    float ss = a0 + a1;
    #pragma unroll
    for (int d = 32; d >= 1; d >>= 1) ss += __shfl_xor(ss, d);
    float inv = 1.0f / powf(ss + 1e-5f, 1.0f / 1.1f);
    if (l < S) msk[wv * S + l] = e0 * inv;
    if (l + 64 < S) msk[wv * S + l + 64] = e1 * inv;
  }
  __syncthreads();

  // ---- phase 1: wx[r][k] = x[bl][k] * msk[m][k] -> f16 (K-pad to 128) -------
  {
    const int r = tid >> 3;                        // 0..63 ; r = m*16 + bl
    const int j = tid & 7;                         // k-chunk of 16
    const int bl = r & 15, m = r >> 4;
    union { _Float16 h[16]; uint4 u[2]; } o;
    #pragma unroll
    for (int i = 0; i < 16; ++i) {
      const int k = j * 16 + i;
      float v = 0.f;
      if (k < S) v = xs[bl * S + k] * msk[m * S + k];
      o.h[i] = (_Float16)v;
    }
    *(uint4*)&wxs[r * WXP + j * 16]     = o.u[0];
    *(uint4*)&wxs[r * WXP + j * 16 + 8] = o.u[1];
  }
  __syncthreads();

  // ---- main: 4 K-steps; W A-frags from L2 with REGISTER DOUBLE-BUFFER ------
  f32x4 acc1[4][4] = {};                           // [ht][rt] (rt == m)
  f32x4 acc2[4][4] = {};
  const _Float16* w1p = PRE ? w16 + (size_t)g * H * KP : nullptr;
  const _Float16* w2p = PRE ? w1p + WMAT : nullptr;
  const float* W1g = W1f + (size_t)g * H * S;
  const float* W2g = W2f + (size_t)g * H * S;

  if constexpr (PRE) {
    half8 cw1[4], cw2[4];
    #pragma unroll
    for (int ht = 0; ht < 4; ++ht) {               // preload ks=0 frags
      const size_t off = (size_t)(64 * wv + ht * 16 + lo) * KP + 8 * hi;
      cw1[ht] = *(const half8*)&w1p[off];
      cw2[ht] = *(const half8*)&w2p[off];
    }
    #pragma unroll
    for (int ks = 0; ks < 4; ++ks) {
      half8 nw1[4], nw2[4];
      if (ks < 3) {                                // prefetch ks+1 frags
        #pragma unroll
        for (int ht = 0; ht < 4; ++ht) {
          const size_t off =
              (size_t)(64 * wv + ht * 16 + lo) * KP + (ks + 1) * 32 + 8 * hi;
          nw1[ht] = *(const half8*)&w1p[off];
          nw2[ht] = *(const half8*)&w2p[off];
        }
      }
      half8 xf[4];
      #pragma unroll
      for (int rt = 0; rt < 4; ++rt)               // B-frag: col r = rt*16+lo
        xf[rt] = *(const half8*)&wxs[(rt * 16 + lo) * WXP + ks * 32 + 8 * hi];
      #pragma unroll
      for (int ht = 0; ht < 4; ++ht) {
        #pragma unroll
        for (int rt = 0; rt < 4; ++rt) {
          acc1[ht][rt] = __builtin_amdgcn_mfma_f32_16x16x32_f16(cw1[ht], xf[rt], acc1[ht][rt], 0, 0, 0);
          acc2[ht][rt] = __builtin_amdgcn_mfma_f32_16x16x32_f16(cw2[ht], xf[rt], acc2[ht][rt], 0, 0, 0);
        }
      }
      if (ks < 3) {
        #pragma unroll
        for (int ht = 0; ht < 4; ++ht) { cw1[ht] = nw1[ht]; cw2[ht] = nw2[ht]; }
      }
    }
  } else {
    #pragma unroll
    for (int ks = 0; ks < 4; ++ks) {
      half8 xf[4];
      #pragma unroll
      for (int rt = 0; rt < 4; ++rt)
        xf[rt] = *(const half8*)&wxs[(rt * 16 + lo) * WXP + ks * 32 + 8 * hi];
      #pragma unroll
      for (int ht = 0; ht < 4; ++ht) {
        const int hrow = 64 * wv + ht * 16 + lo;
        half8 wf1, wf2;
        const float* s1 = W1g + (size_t)hrow * S + ks * 32 + 8 * hi;
        const float* s2 = W2g + (size_t)hrow * S + ks * 32 + 8 * hi;
        if (ks < 3) {
          wf1 = pk8(*(const float4*)s1, *(const float4*)(s1 + 4));
          wf2 = pk8(*(const float4*)s2, *(const float4*)(s2 + 4));
        } else if (hi == 0) {
          float4 z = make_float4(0.f, 0.f, 0.f, 0.f);
          wf1 = pk8(*(const float4*)s1, z);
          wf2 = pk8(*(const float4*)s2, z);
        } else {
          half8 zz = {};
          wf1 = zz; wf2 = zz;
        }
        #pragma unroll
        for (int rt = 0; rt < 4; ++rt) {
          acc1[ht][rt] = __builtin_amdgcn_mfma_f32_16x16x32_f16(wf1, xf[rt], acc1[ht][rt], 0, 0, 0);
          acc2[ht][rt] = __builtin_amdgcn_mfma_f32_16x16x32_f16(wf2, xf[rt], acc2[ht][rt], 0, 0, 0);
        }
      }
    }
  }
  __syncthreads();                                 // wxs reads done -> overlay ok

  // ---- LN stats: per row r, reduce over h = {wv} x {ht} x {hi} x {rg} -------
  float st1[4], sq1[4], st2[4], sq2[4];
  #pragma unroll
  for (int rt = 0; rt < 4; ++rt) {
    float s1 = 0.f, q1 = 0.f, s2 = 0.f, q2 = 0.f;
    #pragma unroll
    for (int ht = 0; ht < 4; ++ht)
      #pragma unroll
      for (int rg = 0; rg < 4; ++rg) {
        float a = acc1[ht][rt][rg], b = acc2[ht][rt][rg];
        s1 += a; q1 += a * a; s2 += b; q2 += b * b;
      }
    st1[rt] = s1; sq1[rt] = q1; st2[rt] = s2; sq2[rt] = q2;
  }
  #pragma unroll
  for (int d = 16; d <= 32; d <<= 1) {             // sum over hi lane-groups
    #pragma unroll
    for (int rt = 0; rt < 4; ++rt) {
      st1[rt] += __shfl_xor(st1[rt], d); sq1[rt] += __shfl_xor(sq1[rt], d);
      st2[rt] += __shfl_xor(st2[rt], d); sq2[rt] += __shfl_xor(sq2[rt], d);
    }
  }
  if (hi == 0) {                                   // one writer per (row, wave)
    #pragma unroll
    for (int rt = 0; rt < 4; ++rt)
      red[(rt * 16 + lo) * 9 + wv] = make_float4(st1[rt], sq1[rt], st2[rt], sq2[rt]);
  }
  __syncthreads();
  if (tid < 64) {                                  // combine 8 waves per row
    float4 t = make_float4(0.f, 0.f, 0.f, 0.f);
    #pragma unroll
    for (int j = 0; j < 8; ++j) {
      float4 v = red[tid * 9 + j];
      t.x += v.x; t.y += v.y; t.z += v.z; t.w += v.w;
    }
    float mu1 = t.x * (1.f / H), mu2 = t.z * (1.f / H);
    float va = t.y * (1.f / H) - mu1 * mu1;
    float vb = t.w * (1.f / H) - mu2 * mu2;
    fin[tid] = make_float4(mu1, rsqrtf(va + 1e-5f), mu2, rsqrtf(vb + 1e-5f));
  }
  __syncthreads();

  // ---- normalize, sigmoid*relu, sum over m (=rt), store ---------------------
  float4 fr[4];
  #pragma unroll
  for (int rt = 0; rt < 4; ++rt) fr[rt] = fin[rt * 16 + lo];
  const float* p1w = ln1w + g * H; const float* p1b = ln1b + g * H;
  const float* p2w = ln2w + g * H; const float* p2b = ln2b + g * H;
  float* orow = out + (size_t)(b0 + lo) * (G * H) + g * H;
  #pragma unroll
  for (int ht = 0; ht < 4; ++ht) {
    const int hb = 64 * wv + ht * 16 + 4 * hi;
    float4 w1v = *(const float4*)(p1w + hb);
    float4 b1v = *(const float4*)(p1b + hb);
    float4 w2v = *(const float4*)(p2w + hb);
    float4 b2v = *(const float4*)(p2b + hb);
    float o[4] = {0.f, 0.f, 0.f, 0.f};
    #pragma unroll
    for (int rt = 0; rt < 4; ++rt) {
      #pragma unroll
      for (int rg = 0; rg < 4; ++rg) {
        float n1 = (acc1[ht][rt][rg] - fr[rt].x) * fr[rt].y * (&w1v.x)[rg] + (&b1v.x)[rg];
        float n2 = (acc2[ht][rt][rg] - fr[rt].z) * fr[rt].w * (&w2v.x)[rg] + (&b2v.x)[rg];
        float sg = __builtin_amdgcn_rcpf(1.0f + __expf(-n1));
        o[rg] += fmaxf(sg * n2, 0.f);
      }
    }
    *(float4*)(orow + hb) = make_float4(o[0], o[1], o[2], o[3]);
  }
}

extern "C" void kernel_launch(void* const* d_in, const int* in_sizes, int n_in,
                              void* d_out, int out_size, void* d_ws, size_t ws_size,
                              hipStream_t stream) {
  const float* x   = (const float*)d_in[0];
  const float* Wm  = (const float*)d_in[1];
  const float* W1  = (const float*)d_in[2];
  const float* W2  = (const float*)d_in[3];
  const float* l1w = (const float*)d_in[4];
  const float* l1b = (const float*)d_in[5];
  const float* l2w = (const float*)d_in[6];
  const float* l2b = (const float*)d_in[7];
  float* outp = (float*)d_out;

  const dim3 grid((BATCH / BB) * G);
  if (ws_size >= W16_BYTES && d_ws != nullptr) {
    _Float16* w16 = (_Float16*)d_ws;
    const int cvt_threads = 2 * G * H * (KP / 8);  // 163840
    cvt_w_kernel<<<cvt_threads / 256, 256, 0, stream>>>(W1, W2, w16);
    dfg_mfma4_kernel<true><<<grid, NT, 0, stream>>>(
        x, Wm, w16, W1, W2, l1w, l1b, l2w, l2b, outp);
  } else {
    dfg_mfma4_kernel<false><<<grid, NT, 0, stream>>>(
        x, Wm, nullptr, W1, W2, l1w, l1b, l2w, l2b, outp);
  }
}